// Round 3
// baseline (1238.701 us; speedup 1.0000x reference)
//
#include <hip/hip_runtime.h>
#include <math.h>

typedef __attribute__((ext_vector_type(8))) short bf16x8;
typedef __attribute__((ext_vector_type(4))) float f32x4;

// ---------------- workspace layout ----------------
// ushort region (bf16 packed weights), offsets in ushorts:
#define UOFF_CAW 0L        // conv A  [l8][mp4][tap9][ic4][split2][mt2][lane64][e8] = 2359296 bf16
#define UOFF_FAW 2359296L  // fusion A [l8][fm2 8][ic4][split2][mt2][lane64][e8]   =  524288 bf16
#define UOFF_H1W 2883584L  // h1 A [blk2][mp8][slab8][ic4][split2][mt2][lane64][e8]= 1048576 bf16
#define NB_TOT   3932160L  // total bf16 elems (= 1966080 floats)
// float region, offsets in floats:
#define OFF_W1G  1966080L  // [c256][o512] = 131072
#define OFF_W2S  2097152L  // [wv16][i256][o8] = 32768
#define OFF_GRAW 2129920L  // [512][256] = 131072
#define OFF_HG   2260992L  // [512][512] = 262144
#define OFF_DYN  2523136L  // dynamic: states (granule images, 131072 f/poly) + h1 (65536 f/poly)
#define REPACK_N 4096000L  // NB_TOT + 131072 + 32768

// ---------------- helpers ----------------
__device__ inline ushort f2bf_rne(float x) {
  uint u = __float_as_uint(x);
  return (ushort)((u + 0x7FFFu + ((u >> 16) & 1u)) >> 16);
}
__device__ inline void split_bf(float x, ushort& h, ushort& l) {
  uint u = __float_as_uint(x);
  uint hb = (u + 0x7FFFu + ((u >> 16) & 1u)) & 0xFFFF0000u;
  h = (ushort)(hb >> 16);
  l = f2bf_rne(x - __uint_as_float(hb));
}
__device__ inline ushort bfsel(float w, int split) {
  uint u = __float_as_uint(w);
  uint hb = (u + 0x7FFFu + ((u >> 16) & 1u)) & 0xFFFF0000u;
  if (split == 0) return (ushort)(hb >> 16);
  float lo = w - __uint_as_float(hb);
  uint ul = __float_as_uint(lo);
  return (ushort)((ul + 0x7FFFu + ((ul >> 16) & 1u)) >> 16);
}
__device__ inline bf16x8 asb(uint4 a) {
  union { uint4 u; bf16x8 v; } x; x.u = a; return x.v;
}
__device__ inline f32x4 MFMA_(bf16x8 a, bf16x8 b, f32x4 c) {
  return __builtin_amdgcn_mfma_f32_16x16x32_bf16(a, b, c, 0, 0, 0);
}
// lgkm-only barrier: does NOT drain vmcnt -> global stores / weight prefetch stay in flight.
__device__ inline void bar_lgkm() {
  asm volatile("s_waitcnt lgkmcnt(0)" ::: "memory");
  __builtin_amdgcn_s_barrier();
}

// LDS x-tile layout (64 KB): per position p (128 rows of 512 B), 16 hi-granules (16 B) + 16 lo-granules.
// Granule (ic,g) holds bf16 of ch ic*32 + {4g..4g+3, 16+4g..16+4g+3} at byte (ic*64+g*16) ^ ((p&7)<<4);
// lo-plane at +256 B. XOR swizzle makes stride-512B column reads bank-uniform.
__device__ inline void read_frag_pair(const char* xb, int pc, int g, int ic,
                                      bf16x8& bh, bf16x8& bl) {
  const int s0 = (pc & 7) << 4;
  const char* a = xb + pc * 512 + (((ic * 64 + (g << 4))) ^ s0);
  bh = asb(*(const uint4*)a);
  bl = asb(*(const uint4*)(a + 256));
}

// ---------------- repack: split weights to bf16 hi/lo in MFMA fragment order (unchanged) ----------------
__global__ void k_repack(const float* __restrict__ head_w, const float* __restrict__ res_w,
                         const float* __restrict__ fusion_w,
                         const float* __restrict__ pred1_w, const float* __restrict__ cls1_w,
                         const float* __restrict__ pred2_w, const float* __restrict__ cls2_w,
                         float* __restrict__ ws) {
  const long j = (long)blockIdx.x * 256 + threadIdx.x;
  if (j >= REPACK_N) return;
  if (j < NB_TOT) {
    ushort* wsu = (ushort*)ws;
    float w;
    if (j < UOFF_FAW) {                       // CAW
      int e = (int)(j & 7); long q = j >> 3;
      int lane = (int)(q & 63); q >>= 6;
      int mt = (int)(q & 1); q >>= 1;
      int split = (int)(q & 1); q >>= 1;
      int ic = (int)(q & 3); q >>= 2;
      int tap = (int)(q % 9); q /= 9;
      int mp = (int)(q & 3); int l = (int)(q >> 2);
      int gg = lane >> 4;
      int kl = (e < 4) ? (4 * gg + e) : (16 + 4 * gg + e - 4);
      int m = mp * 32 + mt * 16 + (lane & 15);
      int i = ic * 32 + kl;
      if (l == 0) w = (i < 67) ? head_w[((long)m * 67 + i) * 9 + tap] : 0.f;
      else        w = res_w[(((long)(l - 1) * 128 + m) * 128 + i) * 9 + tap];
      wsu[j] = bfsel(w, split);
    } else if (j < UOFF_H1W) {                // FAW
      long jj = j - UOFF_FAW;
      int e = (int)(jj & 7); long q = jj >> 3;
      int lane = (int)(q & 63); q >>= 6;
      int mt = (int)(q & 1); q >>= 1;
      int split = (int)(q & 1); q >>= 1;
      int ic = (int)(q & 3); q >>= 2;
      int fm2 = (int)(q & 7); int l = (int)(q >> 3);
      int gg = lane >> 4;
      int kl = (e < 4) ? (4 * gg + e) : (16 + 4 * gg + e - 4);
      int m = fm2 * 32 + mt * 16 + (lane & 15);
      int i = ic * 32 + kl;
      w = fusion_w[(long)m * 1024 + l * 128 + i];
      wsu[j] = bfsel(w, split);
    } else {                                  // H1W
      long jj = j - UOFF_H1W;
      int e = (int)(jj & 7); long q = jj >> 3;
      int lane = (int)(q & 63); q >>= 6;
      int mt = (int)(q & 1); q >>= 1;
      int split = (int)(q & 1); q >>= 1;
      int ic = (int)(q & 3); q >>= 2;
      int slab = (int)(q & 7); q >>= 3;
      int mp = (int)(q & 7); int blk = (int)(q >> 3);
      int gg = lane >> 4;
      int kl = (e < 4) ? (4 * gg + e) : (16 + 4 * gg + e - 4);
      int m = blk * 256 + mp * 32 + mt * 16 + (lane & 15);
      int k = slab * 128 + ic * 32 + kl;
      w = (m < 256) ? pred1_w[(long)m * 1280 + 256 + k] : cls1_w[(long)(m - 256) * 1280 + 256 + k];
      wsu[j] = bfsel(w, split);
    }
  } else if (j < NB_TOT + 131072) {           // W1G (fp32)
    long q = j - NB_TOT; int o = (int)(q & 511); int c = (int)(q >> 9);
    ws[OFF_W1G + q] = (o < 256) ? pred1_w[(long)o * 1280 + c] : cls1_w[(long)(o - 256) * 1280 + c];
  } else {                                    // W2S (fp32)
    long q = j - NB_TOT - 131072;
    int o = (int)(q & 7); int i = (int)((q >> 3) & 255); int wvv = (int)(q >> 11);
    int jg = wvv * 8 + o;
    ws[OFF_W2S + q] = (jg < 64) ? pred2_w[jg * 256 + i] : cls2_w[(jg - 64) * 256 + i];
  }
}

// ================ K1: gather + 8-layer conv chain (MFMA, M=64xN=16 per wave) ================
__global__ __launch_bounds__(1024) __attribute__((amdgpu_waves_per_eu(4)))
void k_conv(const float* __restrict__ cnn, const float* __restrict__ i_it,
            const float* __restrict__ c_it, const float* __restrict__ cls_in,
            const int* __restrict__ ind,
            const ushort* __restrict__ CAW, const ushort* __restrict__ FAW,
            const float* __restrict__ head_b, const float* __restrict__ res_b,
            float* __restrict__ graw, float* __restrict__ states, int p0) {
  __shared__ uint4 xt4[4096];   // 64 KB granule image
  __shared__ float scr[1024];
  char* xb = (char*)xt4;
  const int ln = blockIdx.x, n = p0 + ln, t = threadIdx.x;
  const int lane = t & 63, li = lane & 15, g = lane >> 4;
  const int wv = __builtin_amdgcn_readfirstlane(t >> 6);
  const int mw = wv & 1, nw = wv >> 1;     // conv: M=64 ch x N=16 pos per wave
  const int fm = wv & 3, fqw = wv >> 2;    // fusion: M=64 of 256 x N=32 pos per wave

  // ---- bilinear gather -> LDS fragment granules ----
  {
    const int p = t & 127, qg = t >> 7;    // qg in 0..7: ic = qg>>1, half = qg&1
    const long nb = (long)n * 128 + p;
    const int sw = p & 7;
    if (qg < 4) {
      const float gx = i_it[nb * 2 + 0] - 0.5f;
      const float gy = i_it[nb * 2 + 1] - 0.5f;
      const float fx = floorf(gx), fy = floorf(gy);
      const float wx = gx - fx, wy = gy - fy;
      const int x0 = (int)fx, y0 = (int)fy, x1 = x0 + 1, y1 = y0 + 1;
      const bool vx0 = (x0 >= 0) & (x0 < 128), vx1 = (x1 >= 0) & (x1 < 128);
      const bool vy0 = (y0 >= 0) & (y0 < 128), vy1 = (y1 >= 0) & (y1 < 128);
      const int x0c = min(max(x0, 0), 127), x1c = min(max(x1, 0), 127);
      const int y0c = min(max(y0, 0), 127), y1c = min(max(y1, 0), 127);
      const float w00 = (vx0 && vy0) ? (1.f - wx) * (1.f - wy) : 0.f;
      const float w01 = (vx1 && vy0) ? wx * (1.f - wy) : 0.f;
      const float w10 = (vx0 && vy1) ? (1.f - wx) * wy : 0.f;
      const float w11 = (vx1 && vy1) ? wx * wy : 0.f;
      const long base = (long)ind[n] * (64L * 16384);
      const int a00 = y0c * 128 + x0c, a01 = y0c * 128 + x1c;
      const int a10 = y1c * 128 + x0c, a11 = y1c * 128 + x1c;
#pragma unroll
      for (int qq = 0; qq < 4; qq++) {
        ushort hh[4], ll[4];
#pragma unroll
        for (int cc = 0; cc < 4; cc++) {
          const int c = qg * 16 + qq * 4 + cc;
          const float* f = cnn + base + (long)c * 16384;
          float x = f[a00] * w00 + f[a01] * w01 + f[a10] * w10 + f[a11] * w11;
          split_bf(x, hh[cc], ll[cc]);
        }
        const int G = ((qg >> 1) * 4 + qq) ^ sw;
        char* a = xb + p * 512 + G * 16 + (qg & 1) * 8;
        *(uint2*)a = make_uint2((uint)hh[0] | ((uint)hh[1] << 16), (uint)hh[2] | ((uint)hh[3] << 16));
        *(uint2*)(a + 256) = make_uint2((uint)ll[0] | ((uint)ll[1] << 16), (uint)ll[2] | ((uint)ll[3] << 16));
      }
    } else {
      // channels 64..127: c_it*4, cls, zeros
#pragma unroll
      for (int qq = 0; qq < 4; qq++) {
        ushort hh[4], ll[4];
        if (qg == 4 && qq == 0) {
          float v0 = c_it[nb * 2 + 0] * 4.f, v1 = c_it[nb * 2 + 1] * 4.f, v2 = cls_in[nb];
          split_bf(v0, hh[0], ll[0]); split_bf(v1, hh[1], ll[1]); split_bf(v2, hh[2], ll[2]);
          hh[3] = 0; ll[3] = 0;
        } else {
          hh[0] = hh[1] = hh[2] = hh[3] = 0; ll[0] = ll[1] = ll[2] = ll[3] = 0;
        }
        const int G = ((qg >> 1) * 4 + qq) ^ sw;
        char* a = xb + p * 512 + G * 16 + (qg & 1) * 8;
        *(uint2*)a = make_uint2((uint)hh[0] | ((uint)hh[1] << 16), (uint)hh[2] | ((uint)hh[3] << 16));
        *(uint2*)(a + 256) = make_uint2((uint)ll[0] | ((uint)ll[1] << 16), (uint)ll[2] | ((uint)ll[3] << 16));
      }
    }
  }
  bar_lgkm();

  const f32x4 fz = {0.f, 0.f, 0.f, 0.f};
  f32x4 facc[4][2];
#pragma unroll
  for (int a = 0; a < 4; a++) { facc[a][0] = fz; facc[a][1] = fz; }

  const uint4* caw = (const uint4*)CAW;
  const uint4* faw = (const uint4*)FAW;
  uint4* stq = (uint4*)(states + (long)ln * 131072);

  for (int l = 0; l < 8; l++) {
    const int dil = (l >= 6) ? 4 : ((l >= 4) ? 2 : 1);
    const int nic = (l == 0) ? 3 : 4;       // layer 0: channels 96..127 are exactly zero
    // ======== conv(l): M=64 (4 m-frags) x N=16, reads xt ========
    f32x4 cacc[4];
    cacc[0] = fz; cacc[1] = fz; cacc[2] = fz; cacc[3] = fz;
    const uint4* cawl = caw + ((long)(l * 4 + mw * 2)) * 9216;
    for (int tap = 0; tap < 9; tap++) {
      const int shift = (tap - 4) * dil;
      const int pc = (nw * 16 + li + shift + 128) & 127;
      const uint4* wt = cawl + tap * 1024 + lane;
      for (int ic = 0; ic < nic; ic++) {
        bf16x8 bh, bl;
        read_frag_pair(xb, pc, g, ic, bh, bl);
        const uint4* w0 = wt + ic * 256;
        const bf16x8 Ah0 = asb(w0[0]),          Ah1 = asb(w0[64]);
        const bf16x8 Al0 = asb(w0[128]),        Al1 = asb(w0[192]);
        const bf16x8 Ah2 = asb(w0[9216]),       Ah3 = asb(w0[9216 + 64]);
        const bf16x8 Al2 = asb(w0[9216 + 128]), Al3 = asb(w0[9216 + 192]);
        cacc[0] = MFMA_(Ah0, bh, cacc[0]);
        cacc[1] = MFMA_(Ah1, bh, cacc[1]);
        cacc[2] = MFMA_(Ah2, bh, cacc[2]);
        cacc[3] = MFMA_(Ah3, bh, cacc[3]);
        cacc[0] = MFMA_(Ah0, bl, cacc[0]);
        cacc[1] = MFMA_(Ah1, bl, cacc[1]);
        cacc[2] = MFMA_(Ah2, bl, cacc[2]);
        cacc[3] = MFMA_(Ah3, bl, cacc[3]);
        cacc[0] = MFMA_(Al0, bh, cacc[0]);
        cacc[1] = MFMA_(Al1, bh, cacc[1]);
        cacc[2] = MFMA_(Al2, bh, cacc[2]);
        cacc[3] = MFMA_(Al3, bh, cacc[3]);
      }
    }
    bar_lgkm();
    // ======== EPILOGUE: bias + relu + residual -> xt granules (full uint4 ops) ========
    {
      const float* bsrc = (l == 0) ? head_b : (res_b + (l - 1) * 128);
      const int p = nw * 16 + li;
      const int sw = (p & 7) << 4;
#pragma unroll
      for (int j = 0; j < 2; j++) {
        const int f0 = 2 * j, f1 = 2 * j + 1;
        const float4 b0 = *(const float4*)&bsrc[mw * 64 + f0 * 16 + g * 4];
        const float4 b1 = *(const float4*)&bsrc[mw * 64 + f1 * 16 + g * 4];
        float v[8];
        v[0] = fmaxf(cacc[f0][0] + b0.x, 0.f);
        v[1] = fmaxf(cacc[f0][1] + b0.y, 0.f);
        v[2] = fmaxf(cacc[f0][2] + b0.z, 0.f);
        v[3] = fmaxf(cacc[f0][3] + b0.w, 0.f);
        v[4] = fmaxf(cacc[f1][0] + b1.x, 0.f);
        v[5] = fmaxf(cacc[f1][1] + b1.y, 0.f);
        v[6] = fmaxf(cacc[f1][2] + b1.z, 0.f);
        v[7] = fmaxf(cacc[f1][3] + b1.w, 0.f);
        char* a = xb + p * 512 + ((((mw * 2 + j) * 4 + g) << 4) ^ sw);
        if (l > 0) {
          const uint4 oh = *(const uint4*)a;
          const uint4 ol = *(const uint4*)(a + 256);
          const uint hw[4] = {oh.x, oh.y, oh.z, oh.w};
          const uint lw[4] = {ol.x, ol.y, ol.z, ol.w};
#pragma unroll
          for (int k = 0; k < 8; k++) {
            const uint hh = (k & 1) ? (hw[k >> 1] & 0xFFFF0000u) : ((hw[k >> 1] & 0xFFFFu) << 16);
            const uint ll = (k & 1) ? (lw[k >> 1] & 0xFFFF0000u) : ((lw[k >> 1] & 0xFFFFu) << 16);
            v[k] += __uint_as_float(hh) + __uint_as_float(ll);
          }
        }
        ushort hh[8], ll[8];
#pragma unroll
        for (int k = 0; k < 8; k++) split_bf(v[k], hh[k], ll[k]);
        *(uint4*)a = make_uint4((uint)hh[0] | ((uint)hh[1] << 16), (uint)hh[2] | ((uint)hh[3] << 16),
                                (uint)hh[4] | ((uint)hh[5] << 16), (uint)hh[6] | ((uint)hh[7] << 16));
        *(uint4*)(a + 256) = make_uint4((uint)ll[0] | ((uint)ll[1] << 16), (uint)ll[2] | ((uint)ll[3] << 16),
                                        (uint)ll[4] | ((uint)ll[5] << 16), (uint)ll[6] | ((uint)ll[7] << 16));
      }
    }
    bar_lgkm();
    // ======== read region: copy(l) + fusion(l); flows into conv(l+1) ========
    {
      uint4* dst = stq + (long)l * 4096;
#pragma unroll
      for (int k = 0; k < 4; k++) dst[k * 1024 + t] = xt4[k * 1024 + t];
      const uint4* fawl = faw + ((long)(l * 8 + fm * 2)) * 1024 + lane;
#pragma unroll
      for (int ic = 0; ic < 4; ic++) {
        const uint4* w0 = fawl + ic * 256;
        const bf16x8 Ah0 = asb(w0[0]),          Ah1 = asb(w0[64]);
        const bf16x8 Al0 = asb(w0[128]),        Al1 = asb(w0[192]);
        const bf16x8 Ah2 = asb(w0[1024]),       Ah3 = asb(w0[1024 + 64]);
        const bf16x8 Al2 = asb(w0[1024 + 128]), Al3 = asb(w0[1024 + 192]);
#pragma unroll
        for (int nt = 0; nt < 2; nt++) {
          const int pc = fqw * 32 + nt * 16 + li;
          bf16x8 bh, bl;
          read_frag_pair(xb, pc, g, ic, bh, bl);
          facc[0][nt] = MFMA_(Ah0, bh, facc[0][nt]);
          facc[1][nt] = MFMA_(Ah1, bh, facc[1][nt]);
          facc[2][nt] = MFMA_(Ah2, bh, facc[2][nt]);
          facc[3][nt] = MFMA_(Ah3, bh, facc[3][nt]);
          facc[0][nt] = MFMA_(Ah0, bl, facc[0][nt]);
          facc[1][nt] = MFMA_(Ah1, bl, facc[1][nt]);
          facc[2][nt] = MFMA_(Ah2, bl, facc[2][nt]);
          facc[3][nt] = MFMA_(Ah3, bl, facc[3][nt]);
          facc[0][nt] = MFMA_(Al0, bh, facc[0][nt]);
          facc[1][nt] = MFMA_(Al1, bh, facc[1][nt]);
          facc[2][nt] = MFMA_(Al2, bh, facc[2][nt]);
          facc[3][nt] = MFMA_(Al3, bh, facc[3][nt]);
        }
      }
    }
  }

  // ---- fusion row-max over 128 positions -> graw ----
#pragma unroll
  for (int f = 0; f < 4; f++) {
#pragma unroll
    for (int r = 0; r < 4; r++) {
      float m = fmaxf(facc[f][0][r], facc[f][1][r]);
#pragma unroll
      for (int s = 1; s < 16; s <<= 1) m = fmaxf(m, __shfl_xor(m, s, 64));
      if (li == 0) scr[(fm * 64 + f * 16 + g * 4 + r) * 4 + fqw] = m;
    }
  }
  bar_lgkm();
  if (t < 256) {
    const float* sc = scr + t * 4;
    graw[(long)n * 256 + t] = fmaxf(fmaxf(sc[0], sc[1]), fmaxf(sc[2], sc[3]));
  }
}

// =============== K_hg: hg[n][o] = bias + W1G[:,o].(graw+fus_b) (unchanged) ===============
__global__ __launch_bounds__(512)
void k_hg(const float* __restrict__ graw, const float* __restrict__ fus_b,
          const float* __restrict__ W1G, const float* __restrict__ p1b, const float* __restrict__ c1b,
          float* __restrict__ hg, int p0) {
  __shared__ float sg[256];
  const int n = p0 + blockIdx.x, t = threadIdx.x;
  if (t < 256) sg[t] = graw[(long)n * 256 + t] + fus_b[t];
  __syncthreads();
  float s = (t < 256) ? p1b[t] : c1b[t - 256];
  const float* w = W1G + t;
#pragma unroll 8
  for (int c = 0; c < 256; c++) s = fmaf(w[(long)c * 512], sg[c], s);
  hg[(long)n * 512 + t] = s;
}

// =============== K2: h1 = relu(W1H @ states + hg), MFMA M=64xN=32, 2 blocks/poly ===============
__global__ __launch_bounds__(1024) __attribute__((amdgpu_waves_per_eu(4)))
void k_h1(const float* __restrict__ states, const ushort* __restrict__ H1W,
          const float* __restrict__ hg, float* __restrict__ h1, int p0) {
  __shared__ uint4 xt4[4096];   // 64 KB, one slab image
  char* xb = (char*)xt4;
  const int b = blockIdx.x, ln = b >> 1, blk = b & 1, t = threadIdx.x;
  const int n = p0 + ln;
  const int lane = t & 63, li = lane & 15, g = lane >> 4;
  const int wv = __builtin_amdgcn_readfirstlane(t >> 6);
  const int mw = wv & 3, qw = wv >> 2;     // M=64 of 256 x N=32 pos
  const uint4* sp = (const uint4*)(states + (long)ln * 131072);
  const uint4* aw = (const uint4*)H1W;
  const f32x4 fz = {0.f, 0.f, 0.f, 0.f};
  f32x4 acc[4][2];
#pragma unroll
  for (int a = 0; a < 4; a++) { acc[a][0] = fz; acc[a][1] = fz; }

  uint4 stg[4];
#pragma unroll
  for (int k = 0; k < 4; k++) stg[k] = sp[k * 1024 + t];

  for (int s = 0; s < 8; s++) {
#pragma unroll
    for (int k = 0; k < 4; k++) xt4[k * 1024 + t] = stg[k];
    bar_lgkm();
    if (s < 7) {
#pragma unroll
      for (int k = 0; k < 4; k++) stg[k] = sp[(s + 1) * 4096 + k * 1024 + t];
    }
    const uint4* awl = aw + (((long)(blk * 8 + mw * 2)) * 8 + s) * 1024 + lane;
#pragma unroll
    for (int ic = 0; ic < 4; ic++) {
      const uint4* w0 = awl + ic * 256;
      const bf16x8 Ah0 = asb(w0[0]),          Ah1 = asb(w0[64]);
      const bf16x8 Al0 = asb(w0[128]),        Al1 = asb(w0[192]);
      const bf16x8 Ah2 = asb(w0[8192]),       Ah3 = asb(w0[8192 + 64]);
      const bf16x8 Al2 = asb(w0[8192 + 128]), Al3 = asb(w0[8192 + 192]);
#pragma unroll
      for (int nt = 0; nt < 2; nt++) {
        const int pc = qw * 32 + nt * 16 + li;
        bf16x8 bh, bl;
        read_frag_pair(xb, pc, g, ic, bh, bl);
        acc[0][nt] = MFMA_(Ah0, bh, acc[0][nt]);
        acc[1][nt] = MFMA_(Ah1, bh, acc[1][nt]);
        acc[2][nt] = MFMA_(Ah2, bh, acc[2][nt]);
        acc[3][nt] = MFMA_(Ah3, bh, acc[3][nt]);
        acc[0][nt] = MFMA_(Ah0, bl, acc[0][nt]);
        acc[1][nt] = MFMA_(Ah1, bl, acc[1][nt]);
        acc[2][nt] = MFMA_(Ah2, bl, acc[2][nt]);
        acc[3][nt] = MFMA_(Ah3, bl, acc[3][nt]);
        acc[0][nt] = MFMA_(Al0, bh, acc[0][nt]);
        acc[1][nt] = MFMA_(Al1, bh, acc[1][nt]);
        acc[2][nt] = MFMA_(Al2, bh, acc[2][nt]);
        acc[3][nt] = MFMA_(Al3, bh, acc[3][nt]);
      }
    }
    bar_lgkm();
  }
  const float* hgp = hg + (long)n * 512;
  float* hb = h1 + (long)ln * 65536;
#pragma unroll
  for (int f = 0; f < 4; f++) {
    const int ob = blk * 256 + mw * 64 + f * 16 + g * 4;
    const float4 hq = *(const float4*)&hgp[ob];
#pragma unroll
    for (int nt = 0; nt < 2; nt++) {
      const int p = qw * 32 + nt * 16 + li;
      float* d = hb + (long)ob * 128 + p;
      d[0]   = fmaxf(acc[f][nt][0] + hq.x, 0.f);
      d[128] = fmaxf(acc[f][nt][1] + hq.y, 0.f);
      d[256] = fmaxf(acc[f][nt][2] + hq.z, 0.f);
      d[384] = fmaxf(acc[f][nt][3] + hq.w, 0.f);
    }
  }
}

// =============== K3: pred2/cls2 + pred3/cls3 + outputs + NMS (unchanged) ===============
__global__ __launch_bounds__(1024) __attribute__((amdgpu_waves_per_eu(4)))
void k_tail(const float* __restrict__ h1, const float* __restrict__ W2S,
            const float* __restrict__ p2b, const float* __restrict__ c2b,
            const float* __restrict__ p3w, const float* __restrict__ p3b,
            const float* __restrict__ c3w, const float* __restrict__ c3b,
            const float* __restrict__ i_it, float* __restrict__ out, int p0) {
  __shared__ float h2[16384];
  __shared__ float xb[2048], xc[2048];
  const int ln = blockIdx.x, n = p0 + ln, t = threadIdx.x;
  const int po = t & 63;
  const int wv = __builtin_amdgcn_readfirstlane(t >> 6);
  const float* h1p = h1 + (long)ln * 65536;
  const float* wbase = W2S + (long)wv * 2048;
  float a0[8], a1[8];
#pragma unroll
  for (int jj = 0; jj < 8; jj++) { a0[jj] = 0.f; a1[jj] = 0.f; }
  for (int c = 0; c < 16; c++) {
    __syncthreads();
    ((float2*)xb)[t] = ((const float2*)(h1p + (long)c * 2048))[t];
    ((float2*)xc)[t] = ((const float2*)(h1p + 32768 + (long)c * 2048))[t];
    __syncthreads();
    const float* xp = (wv < 8) ? xb : xc;
    const float* wc = wbase + c * 128;
#pragma unroll 4
    for (int i = 0; i < 16; i++) {
      const float xv0 = xp[i * 128 + po];
      const float xv1 = xp[i * 128 + po + 64];
      const float* w = wc + i * 8;
#pragma unroll
      for (int jj = 0; jj < 8; jj++) {
        a0[jj] = fmaf(w[jj], xv0, a0[jj]);
        a1[jj] = fmaf(w[jj], xv1, a1[jj]);
      }
    }
  }
#pragma unroll
  for (int jj = 0; jj < 8; jj++) {
    const int j = wv * 8 + jj;
    const float bb = (j < 64) ? p2b[j] : c2b[j - 64];
    h2[j * 128 + po] = fmaxf(a0[jj] + bb, 0.f);
    h2[j * 128 + po + 64] = fmaxf(a1[jj] + bb, 0.f);
  }
  __syncthreads();

  float sig = 0.f;
  const int pp = t & 127;
  if (t < 128) {
    float o0v = p3b[0], o1v = p3b[1], cv = c3b[0];
    for (int j = 0; j < 64; j++) {
      const float hp = h2[j * 128 + pp];
      const float hc = h2[(64 + j) * 128 + pp];
      o0v = fmaf(p3w[j], hp, o0v);
      o1v = fmaf(p3w[64 + j], hp, o1v);
      cv = fmaf(c3w[j], hc, cv);
    }
    const long ip = ((long)n * 128 + pp) * 2;
    out[ip + 0] = i_it[ip + 0] * 4.f + o0v;
    out[ip + 1] = i_it[ip + 1] * 4.f + o1v;
    out[131072 + (long)n * 128 + pp] = cv;
    sig = 1.f / (1.f + expf(-cv));
  }
  __syncthreads();
  if (t < 128) xb[pp] = sig;
  __syncthreads();
  if (t < 128) {
    float m = xb[pp];
#pragma unroll
    for (int s = 1; s <= 2; s++) {
      m = fmaxf(m, xb[(pp + s) & 127]);
      m = fmaxf(m, xb[(pp + 128 - s) & 127]);
    }
    out[196608 + (long)n * 128 + pp] = (sig >= m) ? sig : 0.f;
  }
}

extern "C" void kernel_launch(void* const* d_in, const int* in_sizes, int n_in,
                              void* d_out, int out_size, void* d_ws, size_t ws_size,
                              hipStream_t stream) {
  const float* cnn      = (const float*)d_in[0];
  const float* i_it     = (const float*)d_in[1];
  const float* c_it     = (const float*)d_in[2];
  const float* it_cls   = (const float*)d_in[3];
  const int*   ind      = (const int*)d_in[4];
  const float* head_w   = (const float*)d_in[5];
  const float* head_b   = (const float*)d_in[6];
  const float* res_w    = (const float*)d_in[7];
  const float* res_b    = (const float*)d_in[8];
  const float* fusion_w = (const float*)d_in[9];
  const float* fusion_b = (const float*)d_in[10];
  const float* pred1_w  = (const float*)d_in[11];
  const float* pred1_b  = (const float*)d_in[12];
  const float* pred2_w  = (const float*)d_in[13];
  const float* pred2_b  = (const float*)d_in[14];
  const float* pred3_w  = (const float*)d_in[15];
  const float* pred3_b  = (const float*)d_in[16];
  const float* cls1_w   = (const float*)d_in[17];
  const float* cls1_b   = (const float*)d_in[18];
  const float* cls2_w   = (const float*)d_in[19];
  const float* cls2_b   = (const float*)d_in[20];
  const float* cls3_w   = (const float*)d_in[21];
  const float* cls3_b   = (const float*)d_in[22];
  float* ws = (float*)d_ws;
  float* out = (float*)d_out;
  const ushort* wsu = (const ushort*)d_ws;

  k_repack<<<(int)((REPACK_N + 255) / 256), 256, 0, stream>>>(
      head_w, res_w, fusion_w, pred1_w, cls1_w, pred2_w, cls2_w, ws);

  long avail_f = (long)(ws_size / 4) - OFF_DYN;
  long Cl = avail_f / 196608;
  int C = (Cl >= 512) ? 512 : ((Cl >= 256) ? 256 : (int)(Cl < 1 ? 1 : Cl));
  float* states = ws + OFF_DYN;
  float* h1 = states + (long)C * 131072;

  for (int p0 = 0; p0 < 512; p0 += C) {
    int Cc = (512 - p0 < C) ? (512 - p0) : C;
    k_conv<<<Cc, 1024, 0, stream>>>(cnn, i_it, c_it, it_cls, ind,
                                    wsu + UOFF_CAW, wsu + UOFF_FAW, head_b, res_b,
                                    ws + OFF_GRAW, states, p0);
    k_hg<<<Cc, 512, 0, stream>>>(ws + OFF_GRAW, fusion_b, ws + OFF_W1G,
                                 pred1_b, cls1_b, ws + OFF_HG, p0);
    k_h1<<<2 * Cc, 1024, 0, stream>>>(states, wsu + UOFF_H1W, ws + OFF_HG, h1, p0);
    k_tail<<<Cc, 1024, 0, stream>>>(h1, ws + OFF_W2S, pred2_b, cls2_b,
                                    pred3_w, pred3_b, cls3_w, cls3_b,
                                    i_it, out, p0);
  }
}

// Round 4
// 1100.020 us; speedup vs baseline: 1.1261x; 1.1261x over previous
//
#include <hip/hip_runtime.h>
#include <math.h>

typedef __attribute__((ext_vector_type(8))) short bf16x8;
typedef __attribute__((ext_vector_type(4))) float f32x4;

// ---------------- workspace layout ----------------
// ushort region (bf16 packed weights), offsets in ushorts:
#define UOFF_CAW 0L        // conv A  [l8][mp4][tap9][ic4][split2][mt2][lane64][e8] = 2359296 bf16
#define UOFF_FAW 2359296L  // fusion A [l8][fm2 8][ic4][split2][mt2][lane64][e8]   =  524288 bf16
#define UOFF_H1W 2883584L  // h1 A [blk2][mp8][slab8][ic4][split2][mt2][lane64][e8]= 1048576 bf16
#define NB_TOT   3932160L  // total bf16 elems (= 1966080 floats)
// float region, offsets in floats:
#define OFF_W1G  1966080L  // [c256][o512] = 131072
#define OFF_W2S  2097152L  // [wv16][i256][o8] = 32768
#define OFF_GRAW 2129920L  // [512][256] = 131072
#define OFF_HG   2260992L  // [512][512] = 262144
#define OFF_DYN  2523136L  // dynamic: states (granule images, 131072 f/poly) + h1 (65536 f/poly)
#define REPACK_N 4096000L  // NB_TOT + 131072 + 32768

// ---------------- helpers ----------------
__device__ inline ushort f2bf_rne(float x) {
  uint u = __float_as_uint(x);
  return (ushort)((u + 0x7FFFu + ((u >> 16) & 1u)) >> 16);
}
__device__ inline void split_bf(float x, ushort& h, ushort& l) {
  uint u = __float_as_uint(x);
  uint hb = (u + 0x7FFFu + ((u >> 16) & 1u)) & 0xFFFF0000u;
  h = (ushort)(hb >> 16);
  l = f2bf_rne(x - __uint_as_float(hb));
}
__device__ inline ushort bfsel(float w, int split) {
  uint u = __float_as_uint(w);
  uint hb = (u + 0x7FFFu + ((u >> 16) & 1u)) & 0xFFFF0000u;
  if (split == 0) return (ushort)(hb >> 16);
  float lo = w - __uint_as_float(hb);
  uint ul = __float_as_uint(lo);
  return (ushort)((ul + 0x7FFFu + ((ul >> 16) & 1u)) >> 16);
}
__device__ inline bf16x8 asb(uint4 a) {
  union { uint4 u; bf16x8 v; } x; x.u = a; return x.v;
}
__device__ inline f32x4 MFMA_(bf16x8 a, bf16x8 b, f32x4 c) {
  return __builtin_amdgcn_mfma_f32_16x16x32_bf16(a, b, c, 0, 0, 0);
}
// lgkm-only barrier: does NOT drain vmcnt (weight loads stay in flight).
__device__ inline void bar_lgkm() {
  asm volatile("s_waitcnt lgkmcnt(0)" ::: "memory");
  __builtin_amdgcn_s_barrier();
}

// LDS x-tile layout (64 KB): per position p (128 rows of 512 B), 16 hi-granules (16 B) + 16 lo-granules.
// Granule (ic,g) holds bf16 of ch ic*32 + {4g..4g+3, 16+4g..16+4g+3} at byte (ic*64+g*16) ^ ((p&7)<<4);
// lo-plane at +256 B. XOR swizzle makes stride-512B column reads bank-uniform.
__device__ inline void read_frag_pair(const char* xb, int pc, int g, int ic,
                                      bf16x8& bh, bf16x8& bl) {
  const int s0 = (pc & 7) << 4;
  const char* a = xb + pc * 512 + (((ic * 64 + (g << 4))) ^ s0);
  bh = asb(*(const uint4*)a);
  bl = asb(*(const uint4*)(a + 256));
}

// ---------------- repack: split weights to bf16 hi/lo in MFMA fragment order (unchanged) ----------------
__global__ void k_repack(const float* __restrict__ head_w, const float* __restrict__ res_w,
                         const float* __restrict__ fusion_w,
                         const float* __restrict__ pred1_w, const float* __restrict__ cls1_w,
                         const float* __restrict__ pred2_w, const float* __restrict__ cls2_w,
                         float* __restrict__ ws) {
  const long j = (long)blockIdx.x * 256 + threadIdx.x;
  if (j >= REPACK_N) return;
  if (j < NB_TOT) {
    ushort* wsu = (ushort*)ws;
    float w;
    if (j < UOFF_FAW) {                       // CAW
      int e = (int)(j & 7); long q = j >> 3;
      int lane = (int)(q & 63); q >>= 6;
      int mt = (int)(q & 1); q >>= 1;
      int split = (int)(q & 1); q >>= 1;
      int ic = (int)(q & 3); q >>= 2;
      int tap = (int)(q % 9); q /= 9;
      int mp = (int)(q & 3); int l = (int)(q >> 2);
      int gg = lane >> 4;
      int kl = (e < 4) ? (4 * gg + e) : (16 + 4 * gg + e - 4);
      int m = mp * 32 + mt * 16 + (lane & 15);
      int i = ic * 32 + kl;
      if (l == 0) w = (i < 67) ? head_w[((long)m * 67 + i) * 9 + tap] : 0.f;
      else        w = res_w[(((long)(l - 1) * 128 + m) * 128 + i) * 9 + tap];
      wsu[j] = bfsel(w, split);
    } else if (j < UOFF_H1W) {                // FAW
      long jj = j - UOFF_FAW;
      int e = (int)(jj & 7); long q = jj >> 3;
      int lane = (int)(q & 63); q >>= 6;
      int mt = (int)(q & 1); q >>= 1;
      int split = (int)(q & 1); q >>= 1;
      int ic = (int)(q & 3); q >>= 2;
      int fm2 = (int)(q & 7); int l = (int)(q >> 3);
      int gg = lane >> 4;
      int kl = (e < 4) ? (4 * gg + e) : (16 + 4 * gg + e - 4);
      int m = fm2 * 32 + mt * 16 + (lane & 15);
      int i = ic * 32 + kl;
      w = fusion_w[(long)m * 1024 + l * 128 + i];
      wsu[j] = bfsel(w, split);
    } else {                                  // H1W
      long jj = j - UOFF_H1W;
      int e = (int)(jj & 7); long q = jj >> 3;
      int lane = (int)(q & 63); q >>= 6;
      int mt = (int)(q & 1); q >>= 1;
      int split = (int)(q & 1); q >>= 1;
      int ic = (int)(q & 3); q >>= 2;
      int slab = (int)(q & 7); q >>= 3;
      int mp = (int)(q & 7); int blk = (int)(q >> 3);
      int gg = lane >> 4;
      int kl = (e < 4) ? (4 * gg + e) : (16 + 4 * gg + e - 4);
      int m = blk * 256 + mp * 32 + mt * 16 + (lane & 15);
      int k = slab * 128 + ic * 32 + kl;
      w = (m < 256) ? pred1_w[(long)m * 1280 + 256 + k] : cls1_w[(long)(m - 256) * 1280 + 256 + k];
      wsu[j] = bfsel(w, split);
    }
  } else if (j < NB_TOT + 131072) {           // W1G (fp32)
    long q = j - NB_TOT; int o = (int)(q & 511); int c = (int)(q >> 9);
    ws[OFF_W1G + q] = (o < 256) ? pred1_w[(long)o * 1280 + c] : cls1_w[(long)(o - 256) * 1280 + c];
  } else {                                    // W2S (fp32)
    long q = j - NB_TOT - 131072;
    int o = (int)(q & 7); int i = (int)((q >> 3) & 255); int wvv = (int)(q >> 11);
    int jg = wvv * 8 + o;
    ws[OFF_W2S + q] = (jg < 64) ? pred2_w[jg * 256 + i] : cls2_w[(jg - 64) * 256 + i];
  }
}

// ================ K1: gather + 8-layer conv chain (MFMA, M=32xN=32 per wave) ================
__global__ __launch_bounds__(1024) __attribute__((amdgpu_waves_per_eu(4)))
void k_conv(const float* __restrict__ cnn, const float* __restrict__ i_it,
            const float* __restrict__ c_it, const float* __restrict__ cls_in,
            const int* __restrict__ ind,
            const ushort* __restrict__ CAW, const ushort* __restrict__ FAW,
            const float* __restrict__ head_b, const float* __restrict__ res_b,
            float* __restrict__ graw, float* __restrict__ states, int p0) {
  __shared__ uint4 xt4[4096];   // 64 KB granule image
  __shared__ float scr[512];
  char* xb = (char*)xt4;
  const int ln = blockIdx.x, n = p0 + ln, t = threadIdx.x;
  const int lane = t & 63, li = lane & 15, g = lane >> 4;
  const int wv = __builtin_amdgcn_readfirstlane(t >> 6);
  const int mp = wv & 3, np = wv >> 2;     // conv: M=32 ch x N=32 pos per wave (balanced VMEM/LDS)
  const int fm2 = wv & 7, fq = wv >> 3;    // fusion: M=32 of 256 x N=64 pos per wave

  // ---- bilinear gather -> LDS fragment granules ----
  {
    const int p = t & 127, qg = t >> 7;    // qg in 0..7: ic = qg>>1, half = qg&1
    const long nb = (long)n * 128 + p;
    const int sw = p & 7;
    if (qg < 4) {
      const float gx = i_it[nb * 2 + 0] - 0.5f;
      const float gy = i_it[nb * 2 + 1] - 0.5f;
      const float fx = floorf(gx), fy = floorf(gy);
      const float wx = gx - fx, wy = gy - fy;
      const int x0 = (int)fx, y0 = (int)fy, x1 = x0 + 1, y1 = y0 + 1;
      const bool vx0 = (x0 >= 0) & (x0 < 128), vx1 = (x1 >= 0) & (x1 < 128);
      const bool vy0 = (y0 >= 0) & (y0 < 128), vy1 = (y1 >= 0) & (y1 < 128);
      const int x0c = min(max(x0, 0), 127), x1c = min(max(x1, 0), 127);
      const int y0c = min(max(y0, 0), 127), y1c = min(max(y1, 0), 127);
      const float w00 = (vx0 && vy0) ? (1.f - wx) * (1.f - wy) : 0.f;
      const float w01 = (vx1 && vy0) ? wx * (1.f - wy) : 0.f;
      const float w10 = (vx0 && vy1) ? (1.f - wx) * wy : 0.f;
      const float w11 = (vx1 && vy1) ? wx * wy : 0.f;
      const long base = (long)ind[n] * (64L * 16384);
      const int a00 = y0c * 128 + x0c, a01 = y0c * 128 + x1c;
      const int a10 = y1c * 128 + x0c, a11 = y1c * 128 + x1c;
#pragma unroll
      for (int qq = 0; qq < 4; qq++) {
        ushort hh[4], ll[4];
#pragma unroll
        for (int cc = 0; cc < 4; cc++) {
          const int c = qg * 16 + qq * 4 + cc;
          const float* f = cnn + base + (long)c * 16384;
          float x = f[a00] * w00 + f[a01] * w01 + f[a10] * w10 + f[a11] * w11;
          split_bf(x, hh[cc], ll[cc]);
        }
        const int G = ((qg >> 1) * 4 + qq) ^ sw;
        char* a = xb + p * 512 + G * 16 + (qg & 1) * 8;
        *(uint2*)a = make_uint2((uint)hh[0] | ((uint)hh[1] << 16), (uint)hh[2] | ((uint)hh[3] << 16));
        *(uint2*)(a + 256) = make_uint2((uint)ll[0] | ((uint)ll[1] << 16), (uint)ll[2] | ((uint)ll[3] << 16));
      }
    } else {
      // channels 64..127: c_it*4, cls, zeros
#pragma unroll
      for (int qq = 0; qq < 4; qq++) {
        ushort hh[4], ll[4];
        if (qg == 4 && qq == 0) {
          float v0 = c_it[nb * 2 + 0] * 4.f, v1 = c_it[nb * 2 + 1] * 4.f, v2 = cls_in[nb];
          split_bf(v0, hh[0], ll[0]); split_bf(v1, hh[1], ll[1]); split_bf(v2, hh[2], ll[2]);
          hh[3] = 0; ll[3] = 0;
        } else {
          hh[0] = hh[1] = hh[2] = hh[3] = 0; ll[0] = ll[1] = ll[2] = ll[3] = 0;
        }
        const int G = ((qg >> 1) * 4 + qq) ^ sw;
        char* a = xb + p * 512 + G * 16 + (qg & 1) * 8;
        *(uint2*)a = make_uint2((uint)hh[0] | ((uint)hh[1] << 16), (uint)hh[2] | ((uint)hh[3] << 16));
        *(uint2*)(a + 256) = make_uint2((uint)ll[0] | ((uint)ll[1] << 16), (uint)ll[2] | ((uint)ll[3] << 16));
      }
    }
  }
  __syncthreads();

  const f32x4 fz = {0.f, 0.f, 0.f, 0.f};
  f32x4 facc[2][4];
#pragma unroll
  for (int a = 0; a < 2; a++)
#pragma unroll
    for (int b = 0; b < 4; b++) facc[a][b] = fz;

  const uint4* caw = (const uint4*)CAW;
  const uint4* faw = (const uint4*)FAW;
  uint4* stq = (uint4*)(states + (long)ln * 131072);

  for (int l = 0; l < 8; l++) {
    const int dil = (l >= 6) ? 4 : ((l >= 4) ? 2 : 1);
    const int nic = (l == 0) ? 3 : 4;       // layer 0: channels 96..127 exactly zero
    // ======== READ REGION: fusion(l-1) + conv(l), both read xt ========
    if (l > 0) {
      const uint4* fawl = faw + ((long)((l - 1) * 8 + fm2)) * 1024 + lane;
#pragma unroll
      for (int ic = 0; ic < 4; ic++) {
        const uint4* w0 = fawl + ic * 256;
        const bf16x8 Ah0 = asb(w0[0]),   Ah1 = asb(w0[64]);
        const bf16x8 Al0 = asb(w0[128]), Al1 = asb(w0[192]);
#pragma unroll
        for (int nt = 0; nt < 4; nt++) {
          const int pc = fq * 64 + nt * 16 + li;
          bf16x8 bh, bl;
          read_frag_pair(xb, pc, g, ic, bh, bl);
          facc[0][nt] = MFMA_(Ah0, bh, facc[0][nt]);
          facc[1][nt] = MFMA_(Ah1, bh, facc[1][nt]);
          facc[0][nt] = MFMA_(Ah0, bl, facc[0][nt]);
          facc[1][nt] = MFMA_(Ah1, bl, facc[1][nt]);
          facc[0][nt] = MFMA_(Al0, bh, facc[0][nt]);
          facc[1][nt] = MFMA_(Al1, bh, facc[1][nt]);
        }
      }
    }
    // conv(l): M=32 (2 m-frags) x N=32 (2 n-frags)
    f32x4 cacc[2][2];
    cacc[0][0] = fz; cacc[0][1] = fz; cacc[1][0] = fz; cacc[1][1] = fz;
    const uint4* cawl = caw + ((long)(l * 4 + mp)) * 9216;
    for (int tap = 0; tap < 9; tap++) {
      const int shift = (tap - 4) * dil;
      const int pc0 = (np * 32 + li + shift + 128) & 127;
      const int pc1 = (np * 32 + 16 + li + shift + 128) & 127;
      const uint4* cawt = cawl + tap * 1024 + lane;
      for (int ic = 0; ic < nic; ic++) {
        bf16x8 bh0, bl0, bh1, bl1;
        read_frag_pair(xb, pc0, g, ic, bh0, bl0);
        read_frag_pair(xb, pc1, g, ic, bh1, bl1);
        const uint4* w0 = cawt + ic * 256;
        const bf16x8 Ah0 = asb(w0[0]),   Ah1 = asb(w0[64]);
        const bf16x8 Al0 = asb(w0[128]), Al1 = asb(w0[192]);
        cacc[0][0] = MFMA_(Ah0, bh0, cacc[0][0]);
        cacc[0][1] = MFMA_(Ah0, bh1, cacc[0][1]);
        cacc[1][0] = MFMA_(Ah1, bh0, cacc[1][0]);
        cacc[1][1] = MFMA_(Ah1, bh1, cacc[1][1]);
        cacc[0][0] = MFMA_(Ah0, bl0, cacc[0][0]);
        cacc[0][1] = MFMA_(Ah0, bl1, cacc[0][1]);
        cacc[1][0] = MFMA_(Ah1, bl0, cacc[1][0]);
        cacc[1][1] = MFMA_(Ah1, bl1, cacc[1][1]);
        cacc[0][0] = MFMA_(Al0, bh0, cacc[0][0]);
        cacc[0][1] = MFMA_(Al0, bh1, cacc[0][1]);
        cacc[1][0] = MFMA_(Al1, bh0, cacc[1][0]);
        cacc[1][1] = MFMA_(Al1, bh1, cacc[1][1]);
      }
    }
    bar_lgkm();
    // ======== EPILOGUE: bias + relu + residual -> xt granules + reg-direct states stores ========
    {
      const float* bsrc = (l == 0) ? head_b : (res_b + (l - 1) * 128);
      const float4 b0 = *(const float4*)&bsrc[mp * 32 + g * 4];
      const float4 b1 = *(const float4*)&bsrc[mp * 32 + 16 + g * 4];
#pragma unroll
      for (int nt = 0; nt < 2; nt++) {
        const int p = np * 32 + nt * 16 + li;
        const int X = (mp * 64 + g * 16) ^ ((p & 7) << 4);
        char* a = xb + p * 512 + X;
        float v[8];
        v[0] = fmaxf(cacc[0][nt][0] + b0.x, 0.f);
        v[1] = fmaxf(cacc[0][nt][1] + b0.y, 0.f);
        v[2] = fmaxf(cacc[0][nt][2] + b0.z, 0.f);
        v[3] = fmaxf(cacc[0][nt][3] + b0.w, 0.f);
        v[4] = fmaxf(cacc[1][nt][0] + b1.x, 0.f);
        v[5] = fmaxf(cacc[1][nt][1] + b1.y, 0.f);
        v[6] = fmaxf(cacc[1][nt][2] + b1.z, 0.f);
        v[7] = fmaxf(cacc[1][nt][3] + b1.w, 0.f);
        if (l > 0) {
          const uint4 oh = *(const uint4*)a;
          const uint4 ol = *(const uint4*)(a + 256);
          const uint hw[4] = {oh.x, oh.y, oh.z, oh.w};
          const uint lw[4] = {ol.x, ol.y, ol.z, ol.w};
#pragma unroll
          for (int k = 0; k < 8; k++) {
            const uint hh = (k & 1) ? (hw[k >> 1] & 0xFFFF0000u) : ((hw[k >> 1] & 0xFFFFu) << 16);
            const uint ll = (k & 1) ? (lw[k >> 1] & 0xFFFF0000u) : ((lw[k >> 1] & 0xFFFFu) << 16);
            v[k] += __uint_as_float(hh) + __uint_as_float(ll);
          }
        }
        ushort hh[8], ll[8];
#pragma unroll
        for (int k = 0; k < 8; k++) split_bf(v[k], hh[k], ll[k]);
        const uint4 phi = make_uint4((uint)hh[0] | ((uint)hh[1] << 16), (uint)hh[2] | ((uint)hh[3] << 16),
                                     (uint)hh[4] | ((uint)hh[5] << 16), (uint)hh[6] | ((uint)hh[7] << 16));
        const uint4 plo = make_uint4((uint)ll[0] | ((uint)ll[1] << 16), (uint)ll[2] | ((uint)ll[3] << 16),
                                     (uint)ll[4] | ((uint)ll[5] << 16), (uint)ll[6] | ((uint)ll[7] << 16));
        *(uint4*)a = phi;
        *(uint4*)(a + 256) = plo;
        // reg-direct states store (same granule image layout as xt)
        uint4* sd = stq + (long)l * 4096 + p * 32 + (X >> 4);
        sd[0] = phi;
        sd[16] = plo;
      }
    }
    __syncthreads();   // full drain: xt_l visible AND states stores flushed before next weight burst
  }

  // ======== tail: fusion(7) ========
  {
    const uint4* fawl = faw + ((long)(7 * 8 + fm2)) * 1024 + lane;
#pragma unroll
    for (int ic = 0; ic < 4; ic++) {
      const uint4* w0 = fawl + ic * 256;
      const bf16x8 Ah0 = asb(w0[0]),   Ah1 = asb(w0[64]);
      const bf16x8 Al0 = asb(w0[128]), Al1 = asb(w0[192]);
#pragma unroll
      for (int nt = 0; nt < 4; nt++) {
        const int pc = fq * 64 + nt * 16 + li;
        bf16x8 bh, bl;
        read_frag_pair(xb, pc, g, ic, bh, bl);
        facc[0][nt] = MFMA_(Ah0, bh, facc[0][nt]);
        facc[1][nt] = MFMA_(Ah1, bh, facc[1][nt]);
        facc[0][nt] = MFMA_(Ah0, bl, facc[0][nt]);
        facc[1][nt] = MFMA_(Ah1, bl, facc[1][nt]);
        facc[0][nt] = MFMA_(Al0, bh, facc[0][nt]);
        facc[1][nt] = MFMA_(Al1, bh, facc[1][nt]);
      }
    }
  }

  // ---- fusion row-max over 128 positions -> graw ----
#pragma unroll
  for (int mt = 0; mt < 2; mt++) {
#pragma unroll
    for (int r = 0; r < 4; r++) {
      float m = fmaxf(fmaxf(facc[mt][0][r], facc[mt][1][r]),
                      fmaxf(facc[mt][2][r], facc[mt][3][r]));
#pragma unroll
      for (int s = 1; s < 16; s <<= 1) m = fmaxf(m, __shfl_xor(m, s, 64));
      if (li == 0) scr[(fm2 * 32 + mt * 16 + g * 4 + r) * 2 + fq] = m;
    }
  }
  bar_lgkm();
  if (t < 256) graw[(long)n * 256 + t] = fmaxf(scr[2 * t], scr[2 * t + 1]);
}

// =============== K_hg: hg[n][o] = bias + W1G[:,o].(graw+fus_b) (unchanged) ===============
__global__ __launch_bounds__(512)
void k_hg(const float* __restrict__ graw, const float* __restrict__ fus_b,
          const float* __restrict__ W1G, const float* __restrict__ p1b, const float* __restrict__ c1b,
          float* __restrict__ hg, int p0) {
  __shared__ float sg[256];
  const int n = p0 + blockIdx.x, t = threadIdx.x;
  if (t < 256) sg[t] = graw[(long)n * 256 + t] + fus_b[t];
  __syncthreads();
  float s = (t < 256) ? p1b[t] : c1b[t - 256];
  const float* w = W1G + t;
#pragma unroll 8
  for (int c = 0; c < 256; c++) s = fmaf(w[(long)c * 512], sg[c], s);
  hg[(long)n * 512 + t] = s;
}

// =============== K2: h1 = relu(W1H @ states + hg), MFMA M=32xN=64, 2 blocks/poly ===============
__global__ __launch_bounds__(1024) __attribute__((amdgpu_waves_per_eu(4)))
void k_h1(const float* __restrict__ states, const ushort* __restrict__ H1W,
          const float* __restrict__ hg, float* __restrict__ h1, int p0) {
  __shared__ uint4 xt4[4096];   // 64 KB, one slab image (2 blocks/CU)
  char* xb = (char*)xt4;
  const int b = blockIdx.x, ln = b >> 1, blk = b & 1, t = threadIdx.x;
  const int n = p0 + ln;
  const int lane = t & 63, li = lane & 15, g = lane >> 4;
  const int wv = __builtin_amdgcn_readfirstlane(t >> 6);
  const int mw = wv & 7, qw = wv >> 3;     // M=32 of 256 x N=64 pos (min weight traffic)
  const uint4* sp = (const uint4*)(states + (long)ln * 131072);
  const uint4* aw = (const uint4*)H1W;
  const f32x4 fz = {0.f, 0.f, 0.f, 0.f};
  f32x4 acc[2][4];
#pragma unroll
  for (int a = 0; a < 2; a++)
#pragma unroll
    for (int c = 0; c < 4; c++) acc[a][c] = fz;

  uint4 stg[4];
#pragma unroll
  for (int k = 0; k < 4; k++) stg[k] = sp[k * 1024 + t];

  for (int s = 0; s < 8; s++) {
#pragma unroll
    for (int k = 0; k < 4; k++) xt4[k * 1024 + t] = stg[k];
    bar_lgkm();
    if (s < 7) {
#pragma unroll
      for (int k = 0; k < 4; k++) stg[k] = sp[(s + 1) * 4096 + k * 1024 + t];
    }
    const uint4* awl = aw + (((long)(blk * 8 + mw)) * 8 + s) * 1024 + lane;
#pragma unroll
    for (int ic = 0; ic < 4; ic++) {
      const uint4* w0 = awl + ic * 256;
      const bf16x8 Ah0 = asb(w0[0]),   Ah1 = asb(w0[64]);
      const bf16x8 Al0 = asb(w0[128]), Al1 = asb(w0[192]);
#pragma unroll
      for (int nt = 0; nt < 4; nt++) {
        const int pc = qw * 64 + nt * 16 + li;
        bf16x8 bh, bl;
        read_frag_pair(xb, pc, g, ic, bh, bl);
        acc[0][nt] = MFMA_(Ah0, bh, acc[0][nt]);
        acc[1][nt] = MFMA_(Ah1, bh, acc[1][nt]);
        acc[0][nt] = MFMA_(Ah0, bl, acc[0][nt]);
        acc[1][nt] = MFMA_(Ah1, bl, acc[1][nt]);
        acc[0][nt] = MFMA_(Al0, bh, acc[0][nt]);
        acc[1][nt] = MFMA_(Al1, bh, acc[1][nt]);
      }
    }
    bar_lgkm();
  }
  const float* hgp = hg + (long)n * 512;
  float* hb = h1 + (long)ln * 65536;
#pragma unroll
  for (int mt = 0; mt < 2; mt++) {
    const int ob = blk * 256 + mw * 32 + mt * 16 + g * 4;
    const float4 hq = *(const float4*)&hgp[ob];
#pragma unroll
    for (int nt = 0; nt < 4; nt++) {
      const int p = qw * 64 + nt * 16 + li;
      float* d = hb + (long)ob * 128 + p;
      d[0]   = fmaxf(acc[mt][nt][0] + hq.x, 0.f);
      d[128] = fmaxf(acc[mt][nt][1] + hq.y, 0.f);
      d[256] = fmaxf(acc[mt][nt][2] + hq.z, 0.f);
      d[384] = fmaxf(acc[mt][nt][3] + hq.w, 0.f);
    }
  }
}

// =============== K3: pred2/cls2 + pred3/cls3 + outputs + NMS (unchanged) ===============
__global__ __launch_bounds__(1024) __attribute__((amdgpu_waves_per_eu(4)))
void k_tail(const float* __restrict__ h1, const float* __restrict__ W2S,
            const float* __restrict__ p2b, const float* __restrict__ c2b,
            const float* __restrict__ p3w, const float* __restrict__ p3b,
            const float* __restrict__ c3w, const float* __restrict__ c3b,
            const float* __restrict__ i_it, float* __restrict__ out, int p0) {
  __shared__ float h2[16384];
  __shared__ float xb[2048], xc[2048];
  const int ln = blockIdx.x, n = p0 + ln, t = threadIdx.x;
  const int po = t & 63;
  const int wv = __builtin_amdgcn_readfirstlane(t >> 6);
  const float* h1p = h1 + (long)ln * 65536;
  const float* wbase = W2S + (long)wv * 2048;
  float a0[8], a1[8];
#pragma unroll
  for (int jj = 0; jj < 8; jj++) { a0[jj] = 0.f; a1[jj] = 0.f; }
  for (int c = 0; c < 16; c++) {
    __syncthreads();
    ((float2*)xb)[t] = ((const float2*)(h1p + (long)c * 2048))[t];
    ((float2*)xc)[t] = ((const float2*)(h1p + 32768 + (long)c * 2048))[t];
    __syncthreads();
    const float* xp = (wv < 8) ? xb : xc;
    const float* wc = wbase + c * 128;
#pragma unroll 4
    for (int i = 0; i < 16; i++) {
      const float xv0 = xp[i * 128 + po];
      const float xv1 = xp[i * 128 + po + 64];
      const float* w = wc + i * 8;
#pragma unroll
      for (int jj = 0; jj < 8; jj++) {
        a0[jj] = fmaf(w[jj], xv0, a0[jj]);
        a1[jj] = fmaf(w[jj], xv1, a1[jj]);
      }
    }
  }
#pragma unroll
  for (int jj = 0; jj < 8; jj++) {
    const int j = wv * 8 + jj;
    const float bb = (j < 64) ? p2b[j] : c2b[j - 64];
    h2[j * 128 + po] = fmaxf(a0[jj] + bb, 0.f);
    h2[j * 128 + po + 64] = fmaxf(a1[jj] + bb, 0.f);
  }
  __syncthreads();

  float sig = 0.f;
  const int pp = t & 127;
  if (t < 128) {
    float o0v = p3b[0], o1v = p3b[1], cv = c3b[0];
    for (int j = 0; j < 64; j++) {
      const float hp = h2[j * 128 + pp];
      const float hc = h2[(64 + j) * 128 + pp];
      o0v = fmaf(p3w[j], hp, o0v);
      o1v = fmaf(p3w[64 + j], hp, o1v);
      cv = fmaf(c3w[j], hc, cv);
    }
    const long ip = ((long)n * 128 + pp) * 2;
    out[ip + 0] = i_it[ip + 0] * 4.f + o0v;
    out[ip + 1] = i_it[ip + 1] * 4.f + o1v;
    out[131072 + (long)n * 128 + pp] = cv;
    sig = 1.f / (1.f + expf(-cv));
  }
  __syncthreads();
  if (t < 128) xb[pp] = sig;
  __syncthreads();
  if (t < 128) {
    float m = xb[pp];
#pragma unroll
    for (int s = 1; s <= 2; s++) {
      m = fmaxf(m, xb[(pp + s) & 127]);
      m = fmaxf(m, xb[(pp + 128 - s) & 127]);
    }
    out[196608 + (long)n * 128 + pp] = (sig >= m) ? sig : 0.f;
  }
}

extern "C" void kernel_launch(void* const* d_in, const int* in_sizes, int n_in,
                              void* d_out, int out_size, void* d_ws, size_t ws_size,
                              hipStream_t stream) {
  const float* cnn      = (const float*)d_in[0];
  const float* i_it     = (const float*)d_in[1];
  const float* c_it     = (const float*)d_in[2];
  const float* it_cls   = (const float*)d_in[3];
  const int*   ind      = (const int*)d_in[4];
  const float* head_w   = (const float*)d_in[5];
  const float* head_b   = (const float*)d_in[6];
  const float* res_w    = (const float*)d_in[7];
  const float* res_b    = (const float*)d_in[8];
  const float* fusion_w = (const float*)d_in[9];
  const float* fusion_b = (const float*)d_in[10];
  const float* pred1_w  = (const float*)d_in[11];
  const float* pred1_b  = (const float*)d_in[12];
  const float* pred2_w  = (const float*)d_in[13];
  const float* pred2_b  = (const float*)d_in[14];
  const float* pred3_w  = (const float*)d_in[15];
  const float* pred3_b  = (const float*)d_in[16];
  const float* cls1_w   = (const float*)d_in[17];
  const float* cls1_b   = (const float*)d_in[18];
  const float* cls2_w   = (const float*)d_in[19];
  const float* cls2_b   = (const float*)d_in[20];
  const float* cls3_w   = (const float*)d_in[21];
  const float* cls3_b   = (const float*)d_in[22];
  float* ws = (float*)d_ws;
  float* out = (float*)d_out;
  const ushort* wsu = (const ushort*)d_ws;

  k_repack<<<(int)((REPACK_N + 255) / 256), 256, 0, stream>>>(
      head_w, res_w, fusion_w, pred1_w, cls1_w, pred2_w, cls2_w, ws);

  long avail_f = (long)(ws_size / 4) - OFF_DYN;
  long Cl = avail_f / 196608;
  int C = (Cl >= 512) ? 512 : ((Cl >= 256) ? 256 : (int)(Cl < 1 ? 1 : Cl));
  float* states = ws + OFF_DYN;
  float* h1 = states + (long)C * 131072;

  for (int p0 = 0; p0 < 512; p0 += C) {
    int Cc = (512 - p0 < C) ? (512 - p0) : C;
    k_conv<<<Cc, 1024, 0, stream>>>(cnn, i_it, c_it, it_cls, ind,
                                    wsu + UOFF_CAW, wsu + UOFF_FAW, head_b, res_b,
                                    ws + OFF_GRAW, states, p0);
    k_hg<<<Cc, 512, 0, stream>>>(ws + OFF_GRAW, fusion_b, ws + OFF_W1G,
                                 pred1_b, cls1_b, ws + OFF_HG, p0);
    k_h1<<<2 * Cc, 1024, 0, stream>>>(states, wsu + UOFF_H1W, ws + OFF_HG, h1, p0);
    k_tail<<<Cc, 1024, 0, stream>>>(h1, ws + OFF_W2S, pred2_b, cls2_b,
                                    pred3_w, pred3_b, cls3_w, cls3_b,
                                    i_it, out, p0);
  }
}

// Round 5
// 976.405 us; speedup vs baseline: 1.2686x; 1.1266x over previous
//
#include <hip/hip_runtime.h>
#include <math.h>

typedef __attribute__((ext_vector_type(8))) short bf16x8;
typedef __attribute__((ext_vector_type(4))) float f32x4;

// ---------------- workspace layout ----------------
// ushort region (bf16 packed weights), offsets in ushorts:
#define UOFF_CAW 0L        // conv A  [l8][mp4][tap9][ic4][split2][mt2][lane64][e8] = 2359296 bf16
#define UOFF_FAW 2359296L  // fusion A [l8][fm2 8][ic4][split2][mt2][lane64][e8]   =  524288 bf16
#define UOFF_H1W 2883584L  // h1 A [blk2][mp8][slab8][ic4][split2][mt2][lane64][e8]= 1048576 bf16
#define UOFF_W2F 3932160L  // pred2/cls2 A [blk2][mfr4][ic8][split2][lane64][e8]   =   65536 bf16
#define NB_TOT   3997696L  // total bf16 elems (= 1998848 floats)
// float region, offsets in floats:
#define OFF_W1G  1998848L  // [c256][o512] = 131072
#define OFF_GRAW 2129920L  // [512][256] = 131072
#define OFF_DYN  2260992L  // dynamic: states (granule images, 131072 f/poly) + h2 (16384 f/poly)
#define REPACK_N 4128768L  // NB_TOT + 131072

// ---------------- helpers ----------------
__device__ inline ushort f2bf_rne(float x) {
  uint u = __float_as_uint(x);
  return (ushort)((u + 0x7FFFu + ((u >> 16) & 1u)) >> 16);
}
__device__ inline void split_bf(float x, ushort& h, ushort& l) {
  uint u = __float_as_uint(x);
  uint hb = (u + 0x7FFFu + ((u >> 16) & 1u)) & 0xFFFF0000u;
  h = (ushort)(hb >> 16);
  l = f2bf_rne(x - __uint_as_float(hb));
}
__device__ inline ushort bfsel(float w, int split) {
  uint u = __float_as_uint(w);
  uint hb = (u + 0x7FFFu + ((u >> 16) & 1u)) & 0xFFFF0000u;
  if (split == 0) return (ushort)(hb >> 16);
  float lo = w - __uint_as_float(hb);
  uint ul = __float_as_uint(lo);
  return (ushort)((ul + 0x7FFFu + ((ul >> 16) & 1u)) >> 16);
}
__device__ inline bf16x8 asb(uint4 a) {
  union { uint4 u; bf16x8 v; } x; x.u = a; return x.v;
}
__device__ inline f32x4 MFMA_(bf16x8 a, bf16x8 b, f32x4 c) {
  return __builtin_amdgcn_mfma_f32_16x16x32_bf16(a, b, c, 0, 0, 0);
}
// lgkm-only barrier: does NOT drain vmcnt (weight loads / states stores stay in flight).
__device__ inline void bar_lgkm() {
  asm volatile("s_waitcnt lgkmcnt(0)" ::: "memory");
  __builtin_amdgcn_s_barrier();
}

// Conv-image LDS layout (64 KB): per position p (128 rows of 512 B), 16 hi-granules (16 B) + 16 lo.
// Granule (ic,g) holds bf16 of ch ic*32 + {4g..4g+3, 16+4g..16+4g+3} at byte (ic*64+g*16) ^ ((p&7)<<4);
// lo-plane at +256 B.
__device__ inline void read_frag_pair(const char* xb, int pc, int g, int ic,
                                      bf16x8& bh, bf16x8& bl) {
  const int s0 = (pc & 7) << 4;
  const char* a = xb + pc * 512 + (((ic * 64 + (g << 4))) ^ s0);
  bh = asb(*(const uint4*)a);
  bl = asb(*(const uint4*)(a + 256));
}

// ---------------- repack ----------------
__global__ void k_repack(const float* __restrict__ head_w, const float* __restrict__ res_w,
                         const float* __restrict__ fusion_w,
                         const float* __restrict__ pred1_w, const float* __restrict__ cls1_w,
                         const float* __restrict__ pred2_w, const float* __restrict__ cls2_w,
                         float* __restrict__ ws) {
  const long j = (long)blockIdx.x * 256 + threadIdx.x;
  if (j >= REPACK_N) return;
  if (j < NB_TOT) {
    ushort* wsu = (ushort*)ws;
    float w;
    if (j < UOFF_FAW) {                       // CAW
      int e = (int)(j & 7); long q = j >> 3;
      int lane = (int)(q & 63); q >>= 6;
      int mt = (int)(q & 1); q >>= 1;
      int split = (int)(q & 1); q >>= 1;
      int ic = (int)(q & 3); q >>= 2;
      int tap = (int)(q % 9); q /= 9;
      int mp = (int)(q & 3); int l = (int)(q >> 2);
      int gg = lane >> 4;
      int kl = (e < 4) ? (4 * gg + e) : (16 + 4 * gg + e - 4);
      int m = mp * 32 + mt * 16 + (lane & 15);
      int i = ic * 32 + kl;
      if (l == 0) w = (i < 67) ? head_w[((long)m * 67 + i) * 9 + tap] : 0.f;
      else        w = res_w[(((long)(l - 1) * 128 + m) * 128 + i) * 9 + tap];
      wsu[j] = bfsel(w, split);
    } else if (j < UOFF_H1W) {                // FAW
      long jj = j - UOFF_FAW;
      int e = (int)(jj & 7); long q = jj >> 3;
      int lane = (int)(q & 63); q >>= 6;
      int mt = (int)(q & 1); q >>= 1;
      int split = (int)(q & 1); q >>= 1;
      int ic = (int)(q & 3); q >>= 2;
      int fm2 = (int)(q & 7); int l = (int)(q >> 3);
      int gg = lane >> 4;
      int kl = (e < 4) ? (4 * gg + e) : (16 + 4 * gg + e - 4);
      int m = fm2 * 32 + mt * 16 + (lane & 15);
      int i = ic * 32 + kl;
      w = fusion_w[(long)m * 1024 + l * 128 + i];
      wsu[j] = bfsel(w, split);
    } else if (j < UOFF_W2F) {                // H1W
      long jj = j - UOFF_H1W;
      int e = (int)(jj & 7); long q = jj >> 3;
      int lane = (int)(q & 63); q >>= 6;
      int mt = (int)(q & 1); q >>= 1;
      int split = (int)(q & 1); q >>= 1;
      int ic = (int)(q & 3); q >>= 2;
      int slab = (int)(q & 7); q >>= 3;
      int mp = (int)(q & 7); int blk = (int)(q >> 3);
      int gg = lane >> 4;
      int kl = (e < 4) ? (4 * gg + e) : (16 + 4 * gg + e - 4);
      int m = blk * 256 + mp * 32 + mt * 16 + (lane & 15);
      int k = slab * 128 + ic * 32 + kl;
      w = (m < 256) ? pred1_w[(long)m * 1280 + 256 + k] : cls1_w[(long)(m - 256) * 1280 + 256 + k];
      wsu[j] = bfsel(w, split);
    } else {                                  // W2F (pred2/cls2 A-fragments)
      long jj = j - UOFF_W2F;
      int e = (int)(jj & 7); long q = jj >> 3;
      int lane = (int)(q & 63); q >>= 6;
      int split = (int)(q & 1); q >>= 1;
      int ic = (int)(q & 7); q >>= 3;
      int mfr = (int)(q & 3); int blk = (int)(q >> 2);
      int gg = lane >> 4;
      int kl = (e < 4) ? (4 * gg + e) : (16 + 4 * gg + e - 4);
      int m = mfr * 16 + (lane & 15);
      int k = ic * 32 + kl;
      w = blk ? cls2_w[(long)m * 256 + k] : pred2_w[(long)m * 256 + k];
      wsu[j] = bfsel(w, split);
    }
  } else {                                    // W1G (fp32)
    long q = j - NB_TOT; int o = (int)(q & 511); int c = (int)(q >> 9);
    ws[OFF_W1G + q] = (o < 256) ? pred1_w[(long)o * 1280 + c] : cls1_w[(long)(o - 256) * 1280 + c];
  }
}

// ================ K1: gather + 8-layer conv chain (MFMA, M=32xN=32 per wave) ================
__global__ __launch_bounds__(1024) __attribute__((amdgpu_waves_per_eu(4)))
void k_conv(const float* __restrict__ cnn, const float* __restrict__ i_it,
            const float* __restrict__ c_it, const float* __restrict__ cls_in,
            const int* __restrict__ ind,
            const ushort* __restrict__ CAW, const ushort* __restrict__ FAW,
            const float* __restrict__ head_b, const float* __restrict__ res_b,
            float* __restrict__ graw, float* __restrict__ states, int p0) {
  __shared__ uint4 xt4[4096];   // 64 KB granule image
  __shared__ float scr[512];
  char* xb = (char*)xt4;
  const int ln = blockIdx.x, n = p0 + ln, t = threadIdx.x;
  const int lane = t & 63, li = lane & 15, g = lane >> 4;
  const int wv = __builtin_amdgcn_readfirstlane(t >> 6);
  const int mp = wv & 3, np = wv >> 2;     // conv: M=32 ch x N=32 pos per wave
  const int fm2 = wv & 7, fq = wv >> 3;    // fusion: M=32 of 256 x N=64 pos per wave

  // ---- bilinear gather -> LDS fragment granules ----
  {
    const int p = t & 127, qg = t >> 7;
    const long nb = (long)n * 128 + p;
    const int sw = p & 7;
    if (qg < 4) {
      const float gx = i_it[nb * 2 + 0] - 0.5f;
      const float gy = i_it[nb * 2 + 1] - 0.5f;
      const float fx = floorf(gx), fy = floorf(gy);
      const float wx = gx - fx, wy = gy - fy;
      const int x0 = (int)fx, y0 = (int)fy, x1 = x0 + 1, y1 = y0 + 1;
      const bool vx0 = (x0 >= 0) & (x0 < 128), vx1 = (x1 >= 0) & (x1 < 128);
      const bool vy0 = (y0 >= 0) & (y0 < 128), vy1 = (y1 >= 0) & (y1 < 128);
      const int x0c = min(max(x0, 0), 127), x1c = min(max(x1, 0), 127);
      const int y0c = min(max(y0, 0), 127), y1c = min(max(y1, 0), 127);
      const float w00 = (vx0 && vy0) ? (1.f - wx) * (1.f - wy) : 0.f;
      const float w01 = (vx1 && vy0) ? wx * (1.f - wy) : 0.f;
      const float w10 = (vx0 && vy1) ? (1.f - wx) * wy : 0.f;
      const float w11 = (vx1 && vy1) ? wx * wy : 0.f;
      const long base = (long)ind[n] * (64L * 16384);
      const int a00 = y0c * 128 + x0c, a01 = y0c * 128 + x1c;
      const int a10 = y1c * 128 + x0c, a11 = y1c * 128 + x1c;
#pragma unroll
      for (int qq = 0; qq < 4; qq++) {
        ushort hh[4], ll[4];
#pragma unroll
        for (int cc = 0; cc < 4; cc++) {
          const int c = qg * 16 + qq * 4 + cc;
          const float* f = cnn + base + (long)c * 16384;
          float x = f[a00] * w00 + f[a01] * w01 + f[a10] * w10 + f[a11] * w11;
          split_bf(x, hh[cc], ll[cc]);
        }
        const int G = ((qg >> 1) * 4 + qq) ^ sw;
        char* a = xb + p * 512 + G * 16 + (qg & 1) * 8;
        *(uint2*)a = make_uint2((uint)hh[0] | ((uint)hh[1] << 16), (uint)hh[2] | ((uint)hh[3] << 16));
        *(uint2*)(a + 256) = make_uint2((uint)ll[0] | ((uint)ll[1] << 16), (uint)ll[2] | ((uint)ll[3] << 16));
      }
    } else {
#pragma unroll
      for (int qq = 0; qq < 4; qq++) {
        ushort hh[4], ll[4];
        if (qg == 4 && qq == 0) {
          float v0 = c_it[nb * 2 + 0] * 4.f, v1 = c_it[nb * 2 + 1] * 4.f, v2 = cls_in[nb];
          split_bf(v0, hh[0], ll[0]); split_bf(v1, hh[1], ll[1]); split_bf(v2, hh[2], ll[2]);
          hh[3] = 0; ll[3] = 0;
        } else {
          hh[0] = hh[1] = hh[2] = hh[3] = 0; ll[0] = ll[1] = ll[2] = ll[3] = 0;
        }
        const int G = ((qg >> 1) * 4 + qq) ^ sw;
        char* a = xb + p * 512 + G * 16 + (qg & 1) * 8;
        *(uint2*)a = make_uint2((uint)hh[0] | ((uint)hh[1] << 16), (uint)hh[2] | ((uint)hh[3] << 16));
        *(uint2*)(a + 256) = make_uint2((uint)ll[0] | ((uint)ll[1] << 16), (uint)ll[2] | ((uint)ll[3] << 16));
      }
    }
  }
  __syncthreads();

  const f32x4 fz = {0.f, 0.f, 0.f, 0.f};
  f32x4 facc[2][4];
#pragma unroll
  for (int a = 0; a < 2; a++)
#pragma unroll
    for (int b = 0; b < 4; b++) facc[a][b] = fz;

  const uint4* caw = (const uint4*)CAW;
  const uint4* faw = (const uint4*)FAW;
  uint4* stq = (uint4*)(states + (long)ln * 131072);

  for (int l = 0; l < 8; l++) {
    const int dil = (l >= 6) ? 4 : ((l >= 4) ? 2 : 1);
    const int nic = (l == 0) ? 3 : 4;
    // ======== READ REGION: copy(l-1) + fusion(l-1) + conv(l), all read xt ========
    if (l > 0) {
      uint4* dst = stq + (long)(l - 1) * 4096;
#pragma unroll
      for (int k = 0; k < 4; k++) dst[k * 1024 + t] = xt4[k * 1024 + t];
      const uint4* fawl = faw + ((long)((l - 1) * 8 + fm2)) * 1024 + lane;
#pragma unroll
      for (int ic = 0; ic < 4; ic++) {
        const uint4* w0 = fawl + ic * 256;
        const bf16x8 Ah0 = asb(w0[0]),   Ah1 = asb(w0[64]);
        const bf16x8 Al0 = asb(w0[128]), Al1 = asb(w0[192]);
#pragma unroll
        for (int nt = 0; nt < 4; nt++) {
          const int pc = fq * 64 + nt * 16 + li;
          bf16x8 bh, bl;
          read_frag_pair(xb, pc, g, ic, bh, bl);
          facc[0][nt] = MFMA_(Ah0, bh, facc[0][nt]);
          facc[1][nt] = MFMA_(Ah1, bh, facc[1][nt]);
          facc[0][nt] = MFMA_(Ah0, bl, facc[0][nt]);
          facc[1][nt] = MFMA_(Ah1, bl, facc[1][nt]);
          facc[0][nt] = MFMA_(Al0, bh, facc[0][nt]);
          facc[1][nt] = MFMA_(Al1, bh, facc[1][nt]);
        }
      }
    }
    // conv(l)
    f32x4 cacc[2][2];
    cacc[0][0] = fz; cacc[0][1] = fz; cacc[1][0] = fz; cacc[1][1] = fz;
    const uint4* cawl = caw + ((long)(l * 4 + mp)) * 9216;
    for (int tap = 0; tap < 9; tap++) {
      const int shift = (tap - 4) * dil;
      const int pc0 = (np * 32 + li + shift + 128) & 127;
      const int pc1 = (np * 32 + 16 + li + shift + 128) & 127;
      const uint4* cawt = cawl + tap * 1024 + lane;
      for (int ic = 0; ic < nic; ic++) {
        bf16x8 bh0, bl0, bh1, bl1;
        read_frag_pair(xb, pc0, g, ic, bh0, bl0);
        read_frag_pair(xb, pc1, g, ic, bh1, bl1);
        const uint4* w0 = cawt + ic * 256;
        const bf16x8 Ah0 = asb(w0[0]),   Ah1 = asb(w0[64]);
        const bf16x8 Al0 = asb(w0[128]), Al1 = asb(w0[192]);
        cacc[0][0] = MFMA_(Ah0, bh0, cacc[0][0]);
        cacc[0][1] = MFMA_(Ah0, bh1, cacc[0][1]);
        cacc[1][0] = MFMA_(Ah1, bh0, cacc[1][0]);
        cacc[1][1] = MFMA_(Ah1, bh1, cacc[1][1]);
        cacc[0][0] = MFMA_(Ah0, bl0, cacc[0][0]);
        cacc[0][1] = MFMA_(Ah0, bl1, cacc[0][1]);
        cacc[1][0] = MFMA_(Ah1, bl0, cacc[1][0]);
        cacc[1][1] = MFMA_(Ah1, bl1, cacc[1][1]);
        cacc[0][0] = MFMA_(Al0, bh0, cacc[0][0]);
        cacc[0][1] = MFMA_(Al0, bh1, cacc[0][1]);
        cacc[1][0] = MFMA_(Al1, bh0, cacc[1][0]);
        cacc[1][1] = MFMA_(Al1, bh1, cacc[1][1]);
      }
    }
    bar_lgkm();
    // ======== EPILOGUE: bias + relu + residual -> xt granules ========
    {
      const float* bsrc = (l == 0) ? head_b : (res_b + (l - 1) * 128);
      const float4 b0 = *(const float4*)&bsrc[mp * 32 + g * 4];
      const float4 b1 = *(const float4*)&bsrc[mp * 32 + 16 + g * 4];
#pragma unroll
      for (int nt = 0; nt < 2; nt++) {
        const int p = np * 32 + nt * 16 + li;
        const int X = (mp * 64 + g * 16) ^ ((p & 7) << 4);
        char* a = xb + p * 512 + X;
        float v[8];
        v[0] = fmaxf(cacc[0][nt][0] + b0.x, 0.f);
        v[1] = fmaxf(cacc[0][nt][1] + b0.y, 0.f);
        v[2] = fmaxf(cacc[0][nt][2] + b0.z, 0.f);
        v[3] = fmaxf(cacc[0][nt][3] + b0.w, 0.f);
        v[4] = fmaxf(cacc[1][nt][0] + b1.x, 0.f);
        v[5] = fmaxf(cacc[1][nt][1] + b1.y, 0.f);
        v[6] = fmaxf(cacc[1][nt][2] + b1.z, 0.f);
        v[7] = fmaxf(cacc[1][nt][3] + b1.w, 0.f);
        if (l > 0) {
          const uint4 oh = *(const uint4*)a;
          const uint4 ol = *(const uint4*)(a + 256);
          const uint hw[4] = {oh.x, oh.y, oh.z, oh.w};
          const uint lw[4] = {ol.x, ol.y, ol.z, ol.w};
#pragma unroll
          for (int k = 0; k < 8; k++) {
            const uint hh = (k & 1) ? (hw[k >> 1] & 0xFFFF0000u) : ((hw[k >> 1] & 0xFFFFu) << 16);
            const uint ll = (k & 1) ? (lw[k >> 1] & 0xFFFF0000u) : ((lw[k >> 1] & 0xFFFFu) << 16);
            v[k] += __uint_as_float(hh) + __uint_as_float(ll);
          }
        }
        ushort hh[8], ll[8];
#pragma unroll
        for (int k = 0; k < 8; k++) split_bf(v[k], hh[k], ll[k]);
        *(uint4*)a = make_uint4((uint)hh[0] | ((uint)hh[1] << 16), (uint)hh[2] | ((uint)hh[3] << 16),
                                (uint)hh[4] | ((uint)hh[5] << 16), (uint)hh[6] | ((uint)hh[7] << 16));
        *(uint4*)(a + 256) = make_uint4((uint)ll[0] | ((uint)ll[1] << 16), (uint)ll[2] | ((uint)ll[3] << 16),
                                        (uint)ll[4] | ((uint)ll[5] << 16), (uint)ll[6] | ((uint)ll[7] << 16));
      }
    }
    __syncthreads();
  }

  // ======== tail: copy(7) + fusion(7) ========
  {
    uint4* dst = stq + 7L * 4096;
#pragma unroll
    for (int k = 0; k < 4; k++) dst[k * 1024 + t] = xt4[k * 1024 + t];
    const uint4* fawl = faw + ((long)(7 * 8 + fm2)) * 1024 + lane;
#pragma unroll
    for (int ic = 0; ic < 4; ic++) {
      const uint4* w0 = fawl + ic * 256;
      const bf16x8 Ah0 = asb(w0[0]),   Ah1 = asb(w0[64]);
      const bf16x8 Al0 = asb(w0[128]), Al1 = asb(w0[192]);
#pragma unroll
      for (int nt = 0; nt < 4; nt++) {
        const int pc = fq * 64 + nt * 16 + li;
        bf16x8 bh, bl;
        read_frag_pair(xb, pc, g, ic, bh, bl);
        facc[0][nt] = MFMA_(Ah0, bh, facc[0][nt]);
        facc[1][nt] = MFMA_(Ah1, bh, facc[1][nt]);
        facc[0][nt] = MFMA_(Ah0, bl, facc[0][nt]);
        facc[1][nt] = MFMA_(Ah1, bl, facc[1][nt]);
        facc[0][nt] = MFMA_(Al0, bh, facc[0][nt]);
        facc[1][nt] = MFMA_(Al1, bh, facc[1][nt]);
      }
    }
  }

  // ---- fusion row-max over 128 positions -> graw ----
#pragma unroll
  for (int mt = 0; mt < 2; mt++) {
#pragma unroll
    for (int r = 0; r < 4; r++) {
      float m = fmaxf(fmaxf(facc[mt][0][r], facc[mt][1][r]),
                      fmaxf(facc[mt][2][r], facc[mt][3][r]));
#pragma unroll
      for (int s = 1; s < 16; s <<= 1) m = fmaxf(m, __shfl_xor(m, s, 64));
      if (li == 0) scr[(fm2 * 32 + mt * 16 + g * 4 + r) * 2 + fq] = m;
    }
  }
  bar_lgkm();
  if (t < 256) graw[(long)n * 256 + t] = fmaxf(scr[2 * t], scr[2 * t + 1]);
}

// =============== K2: hg + h1 + pred2/cls2 fused; h1 never leaves the CU ===============
__global__ __launch_bounds__(1024) __attribute__((amdgpu_waves_per_eu(4)))
void k_h1t(const float* __restrict__ states, const ushort* __restrict__ H1W,
           const ushort* __restrict__ W2F,
           const float* __restrict__ graw, const float* __restrict__ fus_b,
           const float* __restrict__ W1G, const float* __restrict__ p1b, const float* __restrict__ c1b,
           const float* __restrict__ p2b, const float* __restrict__ c2b,
           float* __restrict__ h2, int p0) {
  __shared__ uint4 xt4[4096];   // 64 KB: slab staging, then h1 granule halves
  __shared__ float sg[256];
  __shared__ float hg_s[256];
  char* xb = (char*)xt4;
  const int b = blockIdx.x, ln = b >> 1, blk = b & 1, t = threadIdx.x;
  const int n = p0 + ln;
  const int lane = t & 63, li = lane & 15, g = lane >> 4;
  const int wv = __builtin_amdgcn_readfirstlane(t >> 6);
  const int mw = wv & 7, qw = wv >> 3;     // phase B: M=32 of 256 x N=64 pos
  const uint4* sp = (const uint4*)(states + (long)ln * 131072);
  const uint4* aw = (const uint4*)H1W;
  const uint4* w2 = (const uint4*)W2F;
  const f32x4 fz = {0.f, 0.f, 0.f, 0.f};

  uint4 stg[4];
#pragma unroll
  for (int k = 0; k < 4; k++) stg[k] = sp[k * 1024 + t];

  // ---- phase A: hg for this block's 256 rows ----
  if (t < 256) sg[t] = graw[(long)n * 256 + t] + fus_b[t];
  __syncthreads();
  if (t < 256) {
    float s = blk ? c1b[t] : p1b[t];
    const float* w = W1G + blk * 256 + t;
#pragma unroll 8
    for (int c = 0; c < 256; c++) s = fmaf(w[(long)c * 512], sg[c], s);
    hg_s[t] = s;
  }

  // ---- phase B: h1 = W1H @ states (acc in regs) ----
  f32x4 acc[2][4];
#pragma unroll
  for (int a = 0; a < 2; a++)
#pragma unroll
    for (int c = 0; c < 4; c++) acc[a][c] = fz;

  for (int s = 0; s < 8; s++) {
#pragma unroll
    for (int k = 0; k < 4; k++) xt4[k * 1024 + t] = stg[k];
    bar_lgkm();
    if (s < 7) {
#pragma unroll
      for (int k = 0; k < 4; k++) stg[k] = sp[(s + 1) * 4096 + k * 1024 + t];
    }
    const uint4* awl = aw + (((long)(blk * 8 + mw)) * 8 + s) * 1024 + lane;
#pragma unroll
    for (int ic = 0; ic < 4; ic++) {
      const uint4* w0 = awl + ic * 256;
      const bf16x8 Ah0 = asb(w0[0]),   Ah1 = asb(w0[64]);
      const bf16x8 Al0 = asb(w0[128]), Al1 = asb(w0[192]);
#pragma unroll
      for (int nt = 0; nt < 4; nt++) {
        const int pc = qw * 64 + nt * 16 + li;
        bf16x8 bh, bl;
        read_frag_pair(xb, pc, g, ic, bh, bl);
        acc[0][nt] = MFMA_(Ah0, bh, acc[0][nt]);
        acc[1][nt] = MFMA_(Ah1, bh, acc[1][nt]);
        acc[0][nt] = MFMA_(Ah0, bl, acc[0][nt]);
        acc[1][nt] = MFMA_(Ah1, bl, acc[1][nt]);
        acc[0][nt] = MFMA_(Al0, bh, acc[0][nt]);
        acc[1][nt] = MFMA_(Al1, bh, acc[1][nt]);
      }
    }
    bar_lgkm();
  }

  // bias + relu in regs: rows (local) mw*32 + mt*16 + g*4 + e, pos qw*64 + nt*16 + li
  const float4 hq0 = *(const float4*)&hg_s[mw * 32 + g * 4];
  const float4 hq1 = *(const float4*)&hg_s[mw * 32 + 16 + g * 4];
#pragma unroll
  for (int nt = 0; nt < 4; nt++) {
    acc[0][nt][0] = fmaxf(acc[0][nt][0] + hq0.x, 0.f);
    acc[0][nt][1] = fmaxf(acc[0][nt][1] + hq0.y, 0.f);
    acc[0][nt][2] = fmaxf(acc[0][nt][2] + hq0.z, 0.f);
    acc[0][nt][3] = fmaxf(acc[0][nt][3] + hq0.w, 0.f);
    acc[1][nt][0] = fmaxf(acc[1][nt][0] + hq1.x, 0.f);
    acc[1][nt][1] = fmaxf(acc[1][nt][1] + hq1.y, 0.f);
    acc[1][nt][2] = fmaxf(acc[1][nt][2] + hq1.z, 0.f);
    acc[1][nt][3] = fmaxf(acc[1][nt][3] + hq1.w, 0.f);
  }

  // ---- phase C: h2 = relu(W2 @ h1 + b2), per pos-half via LDS granules ----
  // h1-granule image per half: pos pl (64 rows of 1 KB): hi granule (ic,g) at pl*1024 + (ic*64+g*16)^((pl&7)<<4), lo +512.
  const int mfr = wv & 3, nfr = wv >> 2;
  const float* b2 = blk ? c2b : p2b;
  float* hbase = h2 + (long)ln * 16384;
  for (int h = 0; h < 2; h++) {
    bar_lgkm();
    if (qw == h) {
#pragma unroll
      for (int nt = 0; nt < 4; nt++) {
        const int pl = nt * 16 + li;
        char* a = xb + pl * 1024 + ((mw * 64 + g * 16) ^ ((pl & 7) << 4));
        ushort hh[8], ll[8];
#pragma unroll
        for (int e = 0; e < 4; e++) { split_bf(acc[0][nt][e], hh[e], ll[e]); }
#pragma unroll
        for (int e = 0; e < 4; e++) { split_bf(acc[1][nt][e], hh[4 + e], ll[4 + e]); }
        *(uint4*)a = make_uint4((uint)hh[0] | ((uint)hh[1] << 16), (uint)hh[2] | ((uint)hh[3] << 16),
                                (uint)hh[4] | ((uint)hh[5] << 16), (uint)hh[6] | ((uint)hh[7] << 16));
        *(uint4*)(a + 512) = make_uint4((uint)ll[0] | ((uint)ll[1] << 16), (uint)ll[2] | ((uint)ll[3] << 16),
                                        (uint)ll[4] | ((uint)ll[5] << 16), (uint)ll[6] | ((uint)ll[7] << 16));
      }
    }
    bar_lgkm();
    f32x4 a2 = fz;
#pragma unroll
    for (int ic = 0; ic < 8; ic++) {
      const uint4* wb = w2 + (((long)(blk * 4 + mfr) * 8 + ic) * 2) * 64 + lane;
      const bf16x8 Ah = asb(wb[0]), Al = asb(wb[64]);
      const int pl = nfr * 16 + li;
      const char* ba = xb + pl * 1024 + ((ic * 64 + g * 16) ^ ((pl & 7) << 4));
      const bf16x8 bh = asb(*(const uint4*)ba);
      const bf16x8 bl = asb(*(const uint4*)(ba + 512));
      a2 = MFMA_(Ah, bh, a2);
      a2 = MFMA_(Ah, bl, a2);
      a2 = MFMA_(Al, bh, a2);
    }
    const int jl = mfr * 16 + g * 4;
    float* hout = hbase + (long)(blk * 64 + jl) * 128 + h * 64 + nfr * 16 + li;
    hout[0]   = fmaxf(a2[0] + b2[jl + 0], 0.f);
    hout[128] = fmaxf(a2[1] + b2[jl + 1], 0.f);
    hout[256] = fmaxf(a2[2] + b2[jl + 2], 0.f);
    hout[384] = fmaxf(a2[3] + b2[jl + 3], 0.f);
  }
}

// =============== K3: pred3/cls3 + outputs + NMS ===============
__global__ __launch_bounds__(128)
void k_tail2(const float* __restrict__ h2,
             const float* __restrict__ p3w, const float* __restrict__ p3b,
             const float* __restrict__ c3w, const float* __restrict__ c3b,
             const float* __restrict__ i_it, float* __restrict__ out, int p0) {
  __shared__ float sb[128];
  const int ln = blockIdx.x, n = p0 + ln, pp = threadIdx.x;
  const float* hp = h2 + (long)ln * 16384;
  float o0v = p3b[0], o1v = p3b[1], cv = c3b[0];
  for (int j = 0; j < 64; j++) {
    const float hpx = hp[j * 128 + pp];
    const float hcx = hp[(64 + j) * 128 + pp];
    o0v = fmaf(p3w[j], hpx, o0v);
    o1v = fmaf(p3w[64 + j], hpx, o1v);
    cv = fmaf(c3w[j], hcx, cv);
  }
  const long ip = ((long)n * 128 + pp) * 2;
  out[ip + 0] = i_it[ip + 0] * 4.f + o0v;
  out[ip + 1] = i_it[ip + 1] * 4.f + o1v;
  out[131072 + (long)n * 128 + pp] = cv;
  const float sig = 1.f / (1.f + expf(-cv));
  sb[pp] = sig;
  __syncthreads();
  float m = sb[pp];
#pragma unroll
  for (int s = 1; s <= 2; s++) {
    m = fmaxf(m, sb[(pp + s) & 127]);
    m = fmaxf(m, sb[(pp + 128 - s) & 127]);
  }
  out[196608 + (long)n * 128 + pp] = (sig >= m) ? sig : 0.f;
}

extern "C" void kernel_launch(void* const* d_in, const int* in_sizes, int n_in,
                              void* d_out, int out_size, void* d_ws, size_t ws_size,
                              hipStream_t stream) {
  const float* cnn      = (const float*)d_in[0];
  const float* i_it     = (const float*)d_in[1];
  const float* c_it     = (const float*)d_in[2];
  const float* it_cls   = (const float*)d_in[3];
  const int*   ind      = (const int*)d_in[4];
  const float* head_w   = (const float*)d_in[5];
  const float* head_b   = (const float*)d_in[6];
  const float* res_w    = (const float*)d_in[7];
  const float* res_b    = (const float*)d_in[8];
  const float* fusion_w = (const float*)d_in[9];
  const float* fusion_b = (const float*)d_in[10];
  const float* pred1_w  = (const float*)d_in[11];
  const float* pred1_b  = (const float*)d_in[12];
  const float* pred2_w  = (const float*)d_in[13];
  const float* pred2_b  = (const float*)d_in[14];
  const float* pred3_w  = (const float*)d_in[15];
  const float* pred3_b  = (const float*)d_in[16];
  const float* cls1_w   = (const float*)d_in[17];
  const float* cls1_b   = (const float*)d_in[18];
  const float* cls2_w   = (const float*)d_in[19];
  const float* cls2_b   = (const float*)d_in[20];
  const float* cls3_w   = (const float*)d_in[21];
  const float* cls3_b   = (const float*)d_in[22];
  float* ws = (float*)d_ws;
  float* out = (float*)d_out;
  const ushort* wsu = (const ushort*)d_ws;

  k_repack<<<(int)((REPACK_N + 255) / 256), 256, 0, stream>>>(
      head_w, res_w, fusion_w, pred1_w, cls1_w, pred2_w, cls2_w, ws);

  long avail_f = (long)(ws_size / 4) - OFF_DYN;
  long Cl = avail_f / 147456;   // states 131072 + h2 16384 floats per poly
  int C = (Cl >= 512) ? 512 : ((Cl >= 256) ? 256 : (int)(Cl < 1 ? 1 : Cl));
  float* states = ws + OFF_DYN;
  float* h2 = states + (long)C * 131072;

  for (int p0 = 0; p0 < 512; p0 += C) {
    int Cc = (512 - p0 < C) ? (512 - p0) : C;
    k_conv<<<Cc, 1024, 0, stream>>>(cnn, i_it, c_it, it_cls, ind,
                                    wsu + UOFF_CAW, wsu + UOFF_FAW, head_b, res_b,
                                    ws + OFF_GRAW, states, p0);
    k_h1t<<<2 * Cc, 1024, 0, stream>>>(states, wsu + UOFF_H1W, wsu + UOFF_W2F,
                                       ws + OFF_GRAW, fusion_b, ws + OFF_W1G,
                                       pred1_b, cls1_b, pred2_b, cls2_b, h2, p0);
    k_tail2<<<Cc, 128, 0, stream>>>(h2, pred3_w, pred3_b, cls3_w, cls3_b,
                                    i_it, out, p0);
  }
}